// Round 6
// baseline (292.483 us; speedup 1.0000x reference)
//
#include <hip/hip_runtime.h>

#define BBATCH 1024
#define NPAIR 512
#define PP 23      // nodes per frame
#define FF 14
#define DD 256
#define CC 23
#define APAIR 12288   // shorts per pair: 3 mtiles * 8 ks * 512

// LDS byte offsets inside k_layer's union region
#define SL_OFF 0
#define SR_OFF 23920
#define S_OFF  47840
#define GS_OFF 56320
#define SMEM_SZ 58368

typedef __attribute__((ext_vector_type(8))) short bf16x8;
typedef __attribute__((ext_vector_type(4))) float f32x4;

#define GLOAD16(gp, lp) __builtin_amdgcn_global_load_lds( \
    (const __attribute__((address_space(1))) void*)(gp),  \
    (__attribute__((address_space(3))) void*)(lp), 16, 0, 0)

__device__ __forceinline__ short f2bf_rne(float v) {
    unsigned u = __float_as_uint(v);
    unsigned r = (u + 0x7FFFu + ((u >> 16) & 1u)) >> 16;
    return (short)(unsigned short)r;
}
__device__ __forceinline__ float bf2f(short s) {
    return __uint_as_float(((unsigned)(unsigned short)s) << 16);
}

// Pair-packed A: [pair][mt(3)][ks(8)][lane(64)][e(8)] shorts.
// row r = f*23 + i (0..45), lane = (r&15) + ((k&31)>>3)*16, ks = k>>5, e = k&7, mt = r>>4.

// ---------------- weight prep: packed frag-major Wt hi/lo ----------------
__global__ __launch_bounds__(256) void k_prep_w(const float* __restrict__ Wl,
    const float* __restrict__ Wr, short* __restrict__ Bh, short* __restrict__ Bl)
{
    __shared__ float ws[DD][16];
    int bid = blockIdx.x;            // l*32 + ntile
    int ll = bid >> 5, ntile = bid & 31;
    int t = threadIdx.x;
    int n0 = ntile * 16;
    const float* W = (n0 < 256) ? (Wl + (size_t)ll * 65536) : (Wr + (size_t)ll * 65536);
    int c0 = n0 & 255;
    for (int kk = t >> 4; kk < DD; kk += 16)
        ws[kk][t & 15] = W[(size_t)kk * 256 + c0 + (t & 15)];
    __syncthreads();
    size_t base = (size_t)bid * 4096;
    for (int idx = t; idx < 4096; idx += 256) {
        int ks = idx >> 9;
        int lane = (idx >> 3) & 63;
        int e = idx & 7;
        int col = lane & 15;
        int k = ks * 32 + ((lane >> 4) << 3) + e;
        float v = ws[k][col];
        short hi = f2bf_rne(v);
        Bh[base + idx] = hi;
        Bl[base + idx] = f2bf_rne(v - bf2f(hi));
    }
}

// ---------------- input projection -> pair-packed bf16 hi/lo ----------------
__global__ __launch_bounds__(256) void k_in_proj(const float* __restrict__ x,
    const float* __restrict__ Win, const float* __restrict__ bin,
    short* __restrict__ Ah, short* __restrict__ Al)
{
    __shared__ float xs[PP][FF];
    int t = threadIdx.x;
    int frame = blockIdx.x;
    for (int idx = t; idx < PP * FF; idx += 256)
        xs[idx / FF][idx % FF] = x[(size_t)frame * PP * FF + idx];
    __syncthreads();
    float w[FF];
#pragma unroll
    for (int f = 0; f < FF; ++f) w[f] = Win[f * DD + t];
    float bb = bin[t];
    int ks = t >> 5, lhi = ((t & 31) >> 3) << 4, e = t & 7;
    size_t pb = (size_t)(frame >> 1) * APAIR;
    int r0 = (frame & 1) * PP;
#pragma unroll
    for (int i = 0; i < PP; ++i) {
        float acc = bb;
#pragma unroll
        for (int f = 0; f < FF; ++f) acc = fmaf(xs[i][f], w[f], acc);
        int r = r0 + i;
        size_t off = pb + ((size_t)((r >> 4) * 8 + ks) << 9) + ((r & 15) + lhi) * 8 + e;
        short hi = f2bf_rne(acc);
        Ah[off] = hi;
        Al[off] = f2bf_rne(acc - bf2f(hi));
    }
}

// ---------------- fused 2-frame GATv2 layer ----------------
__global__ __launch_bounds__(512, 4) void k_layer(
    short* __restrict__ Ah, short* __restrict__ Al,
    const short* __restrict__ Bh, const short* __restrict__ Bl,
    const float* __restrict__ att, float* __restrict__ g)
{
    // union: phase1 staged A (49152 B) | phase2 sl/sr (47840) + S (8464 overlaps A tail)
    __shared__ __align__(16) char smem[SMEM_SZ];
    short* lsA  = (short*)smem;
    float* sl   = (float*)(smem + SL_OFF);     // [23][260]
    float* sr   = (float*)(smem + SR_OFF);     // [23][260]
    float* S    = (float*)(smem + S_OFF);      // [23][23][4]
    float* gsum = (float*)(smem + GS_OFF);     // [2][256]

    int t = threadIdx.x;
    int pair = blockIdx.x;
    size_t pb = (size_t)pair * APAIR;

    // ---- stage A (hi+lo, 48 KB) into LDS ----
    {
        const short* gAh = Ah + pb + t * 8;
        const short* gAl = Al + pb + t * 8;
#pragma unroll
        for (int pass = 0; pass < 3; ++pass) {
            GLOAD16(gAh + pass * 4096, lsA + pass * 4096 + t * 8);
            GLOAD16(gAl + pass * 4096, lsA + 12288 + pass * 4096 + t * 8);
        }
    }

    int l = t & 63, w = t >> 6;
    const short* pB_h = Bh + (size_t)(w * 4) * 4096 + l * 8;
    const short* pB_l = Bl + (size_t)(w * 4) * 4096 + l * 8;
    const short* lA_h = lsA + l * 8;
    const short* lA_l = lsA + 12288 + l * 8;

    f32x4 acc[3][4];
#pragma unroll
    for (int mt = 0; mt < 3; ++mt)
#pragma unroll
        for (int nt = 0; nt < 4; ++nt) acc[mt][nt] = (f32x4)0.0f;

    __syncthreads();   // staging complete

    // ---- GEMM: M=46(+2 pad), N=512, K=256, hi/lo 3-term ----
#pragma unroll
    for (int ks = 0; ks < 8; ++ks) {
        bf16x8 ah[3], al2[3];
#pragma unroll
        for (int mt = 0; mt < 3; ++mt) {
            ah[mt]  = *(const bf16x8*)(lA_h + (mt * 8 + ks) * 512);
            al2[mt] = *(const bf16x8*)(lA_l + (mt * 8 + ks) * 512);
        }
#pragma unroll
        for (int nt = 0; nt < 4; ++nt) {
            bf16x8 bh = *(const bf16x8*)(pB_h + (nt * 8 + ks) * 512);
            bf16x8 bl = *(const bf16x8*)(pB_l + (nt * 8 + ks) * 512);
#pragma unroll
            for (int mt = 0; mt < 3; ++mt) {
                acc[mt][nt] = __builtin_amdgcn_mfma_f32_16x16x32_bf16(ah[mt], bh, acc[mt][nt], 0, 0, 0);
                acc[mt][nt] = __builtin_amdgcn_mfma_f32_16x16x32_bf16(ah[mt], bl, acc[mt][nt], 0, 0, 0);
                acc[mt][nt] = __builtin_amdgcn_mfma_f32_16x16x32_bf16(al2[mt], bh, acc[mt][nt], 0, 0, 0);
            }
        }
    }
    __syncthreads();   // all waves done reading lsA

    // score-thread mapping: t = chunk*23 + i, chunk in [0,16) of 16 channels
    int sc_chunk = t / 23;
    int sc_i = t - sc_chunk * 23;
    int sc_hh = sc_chunk >> 2;
    int sc_c0 = sc_chunk << 4;
    bool sc_act = (t < 368);

    // ---- per-frame attention ----
    for (int f = 0; f < 2; ++f) {
        // scatter this frame's rows from acc -> sl/sr; zero/init S
#pragma unroll
        for (int mt = 0; mt < 3; ++mt) {
            int rbase = mt * 16 + (l >> 4) * 4;
#pragma unroll
            for (int nt = 0; nt < 4; ++nt) {
                int col = w * 64 + nt * 16 + (l & 15);
                float* dst = (col < 256) ? sl : sr;
                int cc = col & 255;
#pragma unroll
                for (int r2 = 0; r2 < 4; ++r2) {
                    int i = rbase + r2 - f * PP;
                    if (0 <= i && i < PP) dst[i * 260 + cc] = acc[mt][nt][r2];
                }
            }
        }
        for (int idx = t; idx < PP * PP * 4; idx += 512)
            S[idx] = (((idx >> 2) % 24) == 0) ? -1e30f : 0.f;   // diag = -inf
        __syncthreads();

        // scores: (i, chunk) threads; sr/att in regs; sl reads broadcast; ds_add partials
        if (sc_act) {
            float4 av0 = *(const float4*)(att + sc_c0);
            float4 av1 = *(const float4*)(att + sc_c0 + 4);
            float4 av2 = *(const float4*)(att + sc_c0 + 8);
            float4 av3 = *(const float4*)(att + sc_c0 + 12);
            const float* srp = sr + sc_i * 260 + sc_c0;
            float4 rv0 = *(const float4*)(srp);
            float4 rv1 = *(const float4*)(srp + 4);
            float4 rv2 = *(const float4*)(srp + 8);
            float4 rv3 = *(const float4*)(srp + 12);
            for (int j = 0; j < PP; ++j) {
                if (j == sc_i) continue;
                const float* slp = sl + j * 260 + sc_c0;
                float4 l0 = *(const float4*)(slp);
                float4 l1 = *(const float4*)(slp + 4);
                float4 l2 = *(const float4*)(slp + 8);
                float4 l3 = *(const float4*)(slp + 12);
                float p = 0.f, v;
                v = l0.x + rv0.x; v = fmaxf(v, 0.2f * v); p = fmaf(av0.x, v, p);
                v = l0.y + rv0.y; v = fmaxf(v, 0.2f * v); p = fmaf(av0.y, v, p);
                v = l0.z + rv0.z; v = fmaxf(v, 0.2f * v); p = fmaf(av0.z, v, p);
                v = l0.w + rv0.w; v = fmaxf(v, 0.2f * v); p = fmaf(av0.w, v, p);
                v = l1.x + rv1.x; v = fmaxf(v, 0.2f * v); p = fmaf(av1.x, v, p);
                v = l1.y + rv1.y; v = fmaxf(v, 0.2f * v); p = fmaf(av1.y, v, p);
                v = l1.z + rv1.z; v = fmaxf(v, 0.2f * v); p = fmaf(av1.z, v, p);
                v = l1.w + rv1.w; v = fmaxf(v, 0.2f * v); p = fmaf(av1.w, v, p);
                v = l2.x + rv2.x; v = fmaxf(v, 0.2f * v); p = fmaf(av2.x, v, p);
                v = l2.y + rv2.y; v = fmaxf(v, 0.2f * v); p = fmaf(av2.y, v, p);
                v = l2.z + rv2.z; v = fmaxf(v, 0.2f * v); p = fmaf(av2.z, v, p);
                v = l2.w + rv2.w; v = fmaxf(v, 0.2f * v); p = fmaf(av2.w, v, p);
                v = l3.x + rv3.x; v = fmaxf(v, 0.2f * v); p = fmaf(av3.x, v, p);
                v = l3.y + rv3.y; v = fmaxf(v, 0.2f * v); p = fmaf(av3.y, v, p);
                v = l3.z + rv3.z; v = fmaxf(v, 0.2f * v); p = fmaf(av3.z, v, p);
                v = l3.w + rv3.w; v = fmaxf(v, 0.2f * v); p = fmaf(av3.w, v, p);
                atomicAdd(&S[(sc_i * PP + j) * 4 + sc_hh], p);
            }
        }
        __syncthreads();

        // softmax over j for each (i, head)
        if (t < PP * 4) {
            int i = t >> 2, hh = t & 3;
            float m = -1e30f;
#pragma unroll
            for (int j = 0; j < PP; ++j) m = fmaxf(m, S[(i * PP + j) * 4 + hh]);
            float s = 0.f;
#pragma unroll
            for (int j = 0; j < PP; ++j) s += __expf(S[(i * PP + j) * 4 + hh] - m);
            float inv = 1.f / s;
#pragma unroll
            for (int j = 0; j < PP; ++j) {
                float* p = S + (i * PP + j) * 4 + hh;
                *p = __expf(*p - m) * inv;
            }
        }
        __syncthreads();

        // aggregate + residual + elu -> write pair-packed bf16 hi/lo (+ g partial)
        {
            int c = t & 255, ip = t >> 8, hh = c >> 6;
            float slc[PP];
#pragma unroll
            for (int j = 0; j < PP; ++j) slc[j] = sl[j * 260 + c];
            int ksw = c >> 5, lhi = ((c & 31) >> 3) << 4, e = c & 7;
            float fsum = 0.f;
            for (int i = ip; i < PP; i += 2) {
                float accv = 0.f;
#pragma unroll
                for (int j = 0; j < PP; ++j)
                    accv = fmaf(S[(i * PP + j) * 4 + hh], slc[j], accv);
                int r = f * PP + i;
                size_t off = pb + ((size_t)((r >> 4) * 8 + ksw) << 9) + ((r & 15) + lhi) * 8 + e;
                float prev = bf2f(Ah[off]) + bf2f(Al[off]);
                float res = accv + prev;
                float outv = (res > 0.f) ? res : (__expf(res) - 1.f);
                short hi = f2bf_rne(outv);
                Ah[off] = hi;
                Al[off] = f2bf_rne(outv - bf2f(hi));
                fsum += outv;
            }
            if (g) gsum[ip * 256 + c] = fsum;
        }
        __syncthreads();   // regions free for next frame; gsum ready

        if (g && t < DD)
            g[(size_t)(pair * 2 + f) * DD + t] = (gsum[t] + gsum[256 + t]) * (1.0f / 23.0f);
    }
}

// ---------------- EB[c] = E_recv[c] @ Ws1[256:512,:] ----------------
__global__ __launch_bounds__(256) void k_eb(const float* __restrict__ E,
    const float* __restrict__ Ws1, float* __restrict__ EB)
{
    int c = blockIdx.x, t = threadIdx.x;
    float acc = 0.f;
    for (int k = 0; k < DD; ++k)
        acc = fmaf(E[c * DD + k], Ws1[(DD + k) * DD + t], acc);
    EB[c * DD + t] = acc;
}

// ---------------- head: 4 graphs per block ----------------
__global__ __launch_bounds__(256) void k_head(const float* __restrict__ g,
    const float* __restrict__ Wr1, const float* __restrict__ br1,
    const float* __restrict__ Wr2, const float* __restrict__ br2,
    const float* __restrict__ Ws1, const float* __restrict__ bs1,
    const float* __restrict__ Ws2, const float* __restrict__ bs2,
    const float* __restrict__ EB, float* __restrict__ out)
{
    __shared__ float gs[4][DD], t1s[4][DD], gtop[4][DD];
    __shared__ float logits[4][CC], probs[4][CC];
    __shared__ float red[4][4];   // [wave][gg]
    int b0 = blockIdx.x * 4;
    int t = threadIdx.x;
    for (int idx = t; idx < 4 * DD; idx += 256)
        gs[idx >> 8][idx & 255] = g[(size_t)b0 * DD + idx];
    __syncthreads();

    float a1[4] = {0.f, 0.f, 0.f, 0.f}, a2[4] = {0.f, 0.f, 0.f, 0.f};
    for (int k = 0; k < DD; k += 2) {
        float w1a = Wr1[k * DD + t], w1b = Wr1[(k + 1) * DD + t];
        float w2a = Ws1[k * DD + t], w2b = Ws1[(k + 1) * DD + t];
#pragma unroll
        for (int gg = 0; gg < 4; ++gg) {
            float2 gv = *(const float2*)&gs[gg][k];
            a1[gg] = fmaf(gv.x, w1a, a1[gg]);
            a1[gg] = fmaf(gv.y, w1b, a1[gg]);
            a2[gg] = fmaf(gv.x, w2a, a2[gg]);
            a2[gg] = fmaf(gv.y, w2b, a2[gg]);
        }
    }
#pragma unroll
    for (int gg = 0; gg < 4; ++gg) {
        t1s[gg][t] = fmaxf(a1[gg] + br1[t], 0.f);
        gtop[gg][t] = a2[gg] + bs1[t];
    }
    __syncthreads();

    if (t < 4 * CC) {
        int gg = t / CC, c = t - gg * CC;
        float acc = br2[c];
        for (int d = 0; d < DD; ++d) acc = fmaf(t1s[gg][d], Wr2[d * CC + c], acc);
        logits[gg][c] = acc;
    }
    __syncthreads();
    if (t < 4 * CC) {
        int gg = t / CC, c = t - gg * CC;
        float m = -1e30f;
        for (int cc = 0; cc < CC; ++cc) m = fmaxf(m, logits[gg][cc]);
        float s = 0.f;
        for (int cc = 0; cc < CC; ++cc) s += __expf(logits[gg][cc] - m);
        probs[gg][c] = __expf(logits[gg][c] - m) / s;
    }
    __syncthreads();

    float wd = Ws2[t];
    float sacc[4];
#pragma unroll
    for (int gg = 0; gg < 4; ++gg) {
        float gt = gtop[gg][t];
        float acc = 0.f;
#pragma unroll
        for (int c = 0; c < CC; ++c)
            acc = fmaf(probs[gg][c], fmaxf(gt + EB[c * DD + t], 0.f), acc);
        sacc[gg] = acc * wd;
    }
#pragma unroll
    for (int gg = 0; gg < 4; ++gg) {
        float v = sacc[gg];
#pragma unroll
        for (int off = 32; off > 0; off >>= 1) v += __shfl_down(v, off, 64);
        if ((t & 63) == 0) red[t >> 6][gg] = v;
    }
    __syncthreads();
    if (t < 4)
        out[b0 + t] = red[0][t] + red[1][t] + red[2][t] + red[3][t] + bs2[0];
}

extern "C" void kernel_launch(void* const* d_in, const int* in_sizes, int n_in,
                              void* d_out, int out_size, void* d_ws, size_t ws_size,
                              hipStream_t stream)
{
    const float* x     = (const float*)d_in[0];
    const float* Win   = (const float*)d_in[3];
    const float* bin   = (const float*)d_in[4];
    const float* Wl    = (const float*)d_in[5];
    const float* Wr    = (const float*)d_in[6];
    const float* att   = (const float*)d_in[7];
    const float* Wr1   = (const float*)d_in[8];
    const float* br1   = (const float*)d_in[9];
    const float* Wr2   = (const float*)d_in[10];
    const float* br2   = (const float*)d_in[11];
    const float* Erecv = (const float*)d_in[12];
    const float* Ws1   = (const float*)d_in[13];
    const float* bs1   = (const float*)d_in[14];
    const float* Ws2   = (const float*)d_in[15];
    const float* bs2   = (const float*)d_in[16];
    float* out = (float*)d_out;

    short* Ah = (short*)d_ws;                       // [512][12288]
    short* Al = Ah + (size_t)NPAIR * APAIR;
    short* Bh = Al + (size_t)NPAIR * APAIR;         // [3][32][4096]
    short* Bl = Bh + (size_t)3 * 131072;
    float* g  = (float*)(Bl + (size_t)3 * 131072);  // [B][DD]
    float* EB = g + (size_t)BBATCH * DD;            // [CC][DD]

    k_prep_w<<<dim3(96), dim3(256), 0, stream>>>(Wl, Wr, Bh, Bl);
    k_in_proj<<<dim3(BBATCH), dim3(256), 0, stream>>>(x, Win, bin, Ah, Al);

    for (int l = 0; l < 3; ++l) {
        k_layer<<<dim3(NPAIR), dim3(512), 0, stream>>>(Ah, Al,
            Bh + (size_t)l * 131072, Bl + (size_t)l * 131072,
            att + (size_t)l * DD, (l == 2) ? g : nullptr);
    }

    k_eb<<<dim3(CC), dim3(256), 0, stream>>>(Erecv, Ws1, EB);
    k_head<<<dim3(256), dim3(256), 0, stream>>>(g, Wr1, br1, Wr2, br2,
                                                Ws1, bs1, Ws2, bs2, EB, out);
}

// Round 7
// 213.798 us; speedup vs baseline: 1.3680x; 1.3680x over previous
//
#include <hip/hip_runtime.h>

#define BBATCH 1024
#define NPAIR 512
#define PP 23      // nodes per frame
#define FF 14
#define DD 256
#define CC 23
#define APAIR 12288   // shorts per pair: 3 mtiles * 8 ks * 512

// LDS byte offsets inside k_layer's union region
#define SL_OFF 0
#define SR_OFF 23920
#define S_OFF  47840
#define GS_OFF 56304
#define SMEM_SZ 58368

typedef __attribute__((ext_vector_type(8))) short bf16x8;
typedef __attribute__((ext_vector_type(4))) float f32x4;

#define GLOAD16(gp, lp) __builtin_amdgcn_global_load_lds( \
    (const __attribute__((address_space(1))) void*)(gp),  \
    (__attribute__((address_space(3))) void*)(lp), 16, 0, 0)

__device__ __forceinline__ short f2bf_rne(float v) {
    unsigned u = __float_as_uint(v);
    unsigned r = (u + 0x7FFFu + ((u >> 16) & 1u)) >> 16;
    return (short)(unsigned short)r;
}
__device__ __forceinline__ float bf2f(short s) {
    return __uint_as_float(((unsigned)(unsigned short)s) << 16);
}

// Pair-packed A: [pair][mt(3)][ks(8)][lane(64)][e(8)] shorts.
// row r = f*23 + i (0..45), lane = (r&15) + ((k&31)>>3)*16, ks = k>>5, e = k&7, mt = r>>4.

// ---------------- weight prep: packed frag-major Wt hi/lo ----------------
__global__ __launch_bounds__(256) void k_prep_w(const float* __restrict__ Wl,
    const float* __restrict__ Wr, short* __restrict__ Bh, short* __restrict__ Bl)
{
    __shared__ float ws[DD][16];
    int bid = blockIdx.x;            // l*32 + ntile
    int ll = bid >> 5, ntile = bid & 31;
    int t = threadIdx.x;
    int n0 = ntile * 16;
    const float* W = (n0 < 256) ? (Wl + (size_t)ll * 65536) : (Wr + (size_t)ll * 65536);
    int c0 = n0 & 255;
    for (int kk = t >> 4; kk < DD; kk += 16)
        ws[kk][t & 15] = W[(size_t)kk * 256 + c0 + (t & 15)];
    __syncthreads();
    size_t base = (size_t)bid * 4096;
    for (int idx = t; idx < 4096; idx += 256) {
        int ks = idx >> 9;
        int lane = (idx >> 3) & 63;
        int e = idx & 7;
        int col = lane & 15;
        int k = ks * 32 + ((lane >> 4) << 3) + e;
        float v = ws[k][col];
        short hi = f2bf_rne(v);
        Bh[base + idx] = hi;
        Bl[base + idx] = f2bf_rne(v - bf2f(hi));
    }
}

// ---------------- input projection -> pair-packed bf16 hi/lo ----------------
__global__ __launch_bounds__(256) void k_in_proj(const float* __restrict__ x,
    const float* __restrict__ Win, const float* __restrict__ bin,
    short* __restrict__ Ah, short* __restrict__ Al)
{
    __shared__ float xs[PP][FF];
    int t = threadIdx.x;
    int frame = blockIdx.x;
    for (int idx = t; idx < PP * FF; idx += 256)
        xs[idx / FF][idx % FF] = x[(size_t)frame * PP * FF + idx];
    __syncthreads();
    float w[FF];
#pragma unroll
    for (int f = 0; f < FF; ++f) w[f] = Win[f * DD + t];
    float bb = bin[t];
    int ks = t >> 5, lhi = ((t & 31) >> 3) << 4, e = t & 7;
    size_t pb = (size_t)(frame >> 1) * APAIR;
    int r0 = (frame & 1) * PP;
#pragma unroll
    for (int i = 0; i < PP; ++i) {
        float acc = bb;
#pragma unroll
        for (int f = 0; f < FF; ++f) acc = fmaf(xs[i][f], w[f], acc);
        int r = r0 + i;
        size_t off = pb + ((size_t)((r >> 4) * 8 + ks) << 9) + ((r & 15) + lhi) * 8 + e;
        short hi = f2bf_rne(acc);
        Ah[off] = hi;
        Al[off] = f2bf_rne(acc - bf2f(hi));
    }
}

// ---------------- fused 2-frame GATv2 layer ----------------
__global__ __launch_bounds__(512, 4) void k_layer(
    short* __restrict__ Ah, short* __restrict__ Al,
    const short* __restrict__ Bh, const short* __restrict__ Bl,
    const float* __restrict__ att, float* __restrict__ g)
{
    // union: phase1 staged A (49152 B) | phase2 sl/sr (47840) + S + gsum
    __shared__ __align__(16) char smem[SMEM_SZ];
    short* lsA  = (short*)smem;
    float* sl   = (float*)(smem + SL_OFF);     // [23][260]
    float* sr   = (float*)(smem + SR_OFF);     // [23][260]
    float* S    = (float*)(smem + S_OFF);      // [23][23][4]
    float* gsum = (float*)(smem + GS_OFF);     // [2][256]

    int t = threadIdx.x;
    int pair = blockIdx.x;
    size_t pb = (size_t)pair * APAIR;

    // ---- stage A (hi+lo, 48 KB) into LDS ----
    {
        const short* gAh = Ah + pb + t * 8;
        const short* gAl = Al + pb + t * 8;
#pragma unroll
        for (int pass = 0; pass < 3; ++pass) {
            GLOAD16(gAh + pass * 4096, lsA + pass * 4096 + t * 8);
            GLOAD16(gAl + pass * 4096, lsA + 12288 + pass * 4096 + t * 8);
        }
    }

    int l = t & 63, w = t >> 6;
    const short* pB_h = Bh + (size_t)(w * 4) * 4096 + l * 8;
    const short* pB_l = Bl + (size_t)(w * 4) * 4096 + l * 8;
    const short* lA_h = lsA + l * 8;
    const short* lA_l = lsA + 12288 + l * 8;

    f32x4 acc[3][4];
#pragma unroll
    for (int mt = 0; mt < 3; ++mt)
#pragma unroll
        for (int nt = 0; nt < 4; ++nt) acc[mt][nt] = (f32x4)0.0f;

    __syncthreads();   // staging complete

    // ---- GEMM: M=46(+2 pad), N=512, K=256, hi/lo 3-term ----
#pragma unroll
    for (int ks = 0; ks < 8; ++ks) {
        bf16x8 ah[3], al2[3];
#pragma unroll
        for (int mt = 0; mt < 3; ++mt) {
            ah[mt]  = *(const bf16x8*)(lA_h + (mt * 8 + ks) * 512);
            al2[mt] = *(const bf16x8*)(lA_l + (mt * 8 + ks) * 512);
        }
#pragma unroll
        for (int nt = 0; nt < 4; ++nt) {
            bf16x8 bh = *(const bf16x8*)(pB_h + (nt * 8 + ks) * 512);
            bf16x8 bl = *(const bf16x8*)(pB_l + (nt * 8 + ks) * 512);
#pragma unroll
            for (int mt = 0; mt < 3; ++mt) {
                acc[mt][nt] = __builtin_amdgcn_mfma_f32_16x16x32_bf16(ah[mt], bh, acc[mt][nt], 0, 0, 0);
                acc[mt][nt] = __builtin_amdgcn_mfma_f32_16x16x32_bf16(ah[mt], bl, acc[mt][nt], 0, 0, 0);
                acc[mt][nt] = __builtin_amdgcn_mfma_f32_16x16x32_bf16(al2[mt], bh, acc[mt][nt], 0, 0, 0);
            }
        }
    }
    __syncthreads();   // all waves done reading lsA

    // score-thread mapping: t = i*16 + ch (ch = 16-channel chunk)
    int sc_i  = t >> 4;
    int sc_ch = t & 15;
    int sc_hh = sc_ch >> 2;
    int sc_c0 = sc_ch << 4;
    bool sc_act = (t < 368);

    // ---- per-frame attention ----
    for (int f = 0; f < 2; ++f) {
        // scatter this frame's rows from acc -> sl/sr
#pragma unroll
        for (int mt = 0; mt < 3; ++mt) {
            int rbase = mt * 16 + (l >> 4) * 4;
#pragma unroll
            for (int nt = 0; nt < 4; ++nt) {
                int col = w * 64 + nt * 16 + (l & 15);
                float* dst = (col < 256) ? sl : sr;
                int cc = col & 255;
#pragma unroll
                for (int r2 = 0; r2 < 4; ++r2) {
                    int i = rbase + r2 - f * PP;
                    if (0 <= i && i < PP) dst[i * 260 + cc] = acc[mt][nt][r2];
                }
            }
        }
        __syncthreads();

        // scores: sr/att in regs; sl[j] chunk reads broadcast across the 23
        // i-threads; q-partials combined via shfl_xor; lane q==0 writes S.
        if (sc_act) {
            float4 av0 = *(const float4*)(att + sc_c0);
            float4 av1 = *(const float4*)(att + sc_c0 + 4);
            float4 av2 = *(const float4*)(att + sc_c0 + 8);
            float4 av3 = *(const float4*)(att + sc_c0 + 12);
            const float* srp = sr + sc_i * 260 + sc_c0;
            float4 rv0 = *(const float4*)(srp);
            float4 rv1 = *(const float4*)(srp + 4);
            float4 rv2 = *(const float4*)(srp + 8);
            float4 rv3 = *(const float4*)(srp + 12);
            for (int j = 0; j < PP; ++j) {
                const float* slp = sl + j * 260 + sc_c0;
                float4 l0 = *(const float4*)(slp);
                float4 l1 = *(const float4*)(slp + 4);
                float4 l2 = *(const float4*)(slp + 8);
                float4 l3 = *(const float4*)(slp + 12);
                float p = 0.f, v;
                v = l0.x + rv0.x; v = fmaxf(v, 0.2f * v); p = fmaf(av0.x, v, p);
                v = l0.y + rv0.y; v = fmaxf(v, 0.2f * v); p = fmaf(av0.y, v, p);
                v = l0.z + rv0.z; v = fmaxf(v, 0.2f * v); p = fmaf(av0.z, v, p);
                v = l0.w + rv0.w; v = fmaxf(v, 0.2f * v); p = fmaf(av0.w, v, p);
                v = l1.x + rv1.x; v = fmaxf(v, 0.2f * v); p = fmaf(av1.x, v, p);
                v = l1.y + rv1.y; v = fmaxf(v, 0.2f * v); p = fmaf(av1.y, v, p);
                v = l1.z + rv1.z; v = fmaxf(v, 0.2f * v); p = fmaf(av1.z, v, p);
                v = l1.w + rv1.w; v = fmaxf(v, 0.2f * v); p = fmaf(av1.w, v, p);
                v = l2.x + rv2.x; v = fmaxf(v, 0.2f * v); p = fmaf(av2.x, v, p);
                v = l2.y + rv2.y; v = fmaxf(v, 0.2f * v); p = fmaf(av2.y, v, p);
                v = l2.z + rv2.z; v = fmaxf(v, 0.2f * v); p = fmaf(av2.z, v, p);
                v = l2.w + rv2.w; v = fmaxf(v, 0.2f * v); p = fmaf(av2.w, v, p);
                v = l3.x + rv3.x; v = fmaxf(v, 0.2f * v); p = fmaf(av3.x, v, p);
                v = l3.y + rv3.y; v = fmaxf(v, 0.2f * v); p = fmaf(av3.y, v, p);
                v = l3.z + rv3.z; v = fmaxf(v, 0.2f * v); p = fmaf(av3.z, v, p);
                v = l3.w + rv3.w; v = fmaxf(v, 0.2f * v); p = fmaf(av3.w, v, p);
                p += __shfl_xor(p, 1, 64);
                p += __shfl_xor(p, 2, 64);
                if ((t & 3) == 0)
                    S[(sc_i * PP + j) * 4 + sc_hh] = (j == sc_i) ? -1e30f : p;
            }
        }
        __syncthreads();

        // softmax over j for each (i, head)
        if (t < PP * 4) {
            int i = t >> 2, hh = t & 3;
            float m = -1e30f;
#pragma unroll
            for (int j = 0; j < PP; ++j) m = fmaxf(m, S[(i * PP + j) * 4 + hh]);
            float s = 0.f;
#pragma unroll
            for (int j = 0; j < PP; ++j) s += __expf(S[(i * PP + j) * 4 + hh] - m);
            float inv = 1.f / s;
#pragma unroll
            for (int j = 0; j < PP; ++j) {
                float* p = S + (i * PP + j) * 4 + hh;
                *p = __expf(*p - m) * inv;
            }
        }
        __syncthreads();

        // aggregate + residual + elu -> write pair-packed bf16 hi/lo (+ g partial)
        {
            int c = t & 255, ip = t >> 8, hh = c >> 6;
            float slc[PP];
#pragma unroll
            for (int j = 0; j < PP; ++j) slc[j] = sl[j * 260 + c];
            int ksw = c >> 5, lhi = ((c & 31) >> 3) << 4, e = c & 7;
            float fsum = 0.f;
            for (int i = ip; i < PP; i += 2) {
                float accv = 0.f;
#pragma unroll
                for (int j = 0; j < PP; ++j)
                    accv = fmaf(S[(i * PP + j) * 4 + hh], slc[j], accv);
                int r = f * PP + i;
                size_t off = pb + ((size_t)((r >> 4) * 8 + ksw) << 9) + ((r & 15) + lhi) * 8 + e;
                float prev = bf2f(Ah[off]) + bf2f(Al[off]);
                float res = accv + prev;
                float outv = (res > 0.f) ? res : (__expf(res) - 1.f);
                short hi = f2bf_rne(outv);
                Ah[off] = hi;
                Al[off] = f2bf_rne(outv - bf2f(hi));
                fsum += outv;
            }
            if (g) gsum[ip * 256 + c] = fsum;
        }
        __syncthreads();   // regions free for next frame; gsum ready

        if (g && t < DD)
            g[(size_t)(pair * 2 + f) * DD + t] = (gsum[t] + gsum[256 + t]) * (1.0f / 23.0f);
    }
}

// ---------------- EB[c] = E_recv[c] @ Ws1[256:512,:] ----------------
__global__ __launch_bounds__(256) void k_eb(const float* __restrict__ E,
    const float* __restrict__ Ws1, float* __restrict__ EB)
{
    int c = blockIdx.x, t = threadIdx.x;
    float acc = 0.f;
    for (int k = 0; k < DD; ++k)
        acc = fmaf(E[c * DD + k], Ws1[(DD + k) * DD + t], acc);
    EB[c * DD + t] = acc;
}

// ---------------- head: 4 graphs per block ----------------
__global__ __launch_bounds__(256) void k_head(const float* __restrict__ g,
    const float* __restrict__ Wr1, const float* __restrict__ br1,
    const float* __restrict__ Wr2, const float* __restrict__ br2,
    const float* __restrict__ Ws1, const float* __restrict__ bs1,
    const float* __restrict__ Ws2, const float* __restrict__ bs2,
    const float* __restrict__ EB, float* __restrict__ out)
{
    __shared__ float gs[4][DD], t1s[4][DD], gtop[4][DD];
    __shared__ float logits[4][CC], probs[4][CC];
    __shared__ float red[4][4];   // [wave][gg]
    int b0 = blockIdx.x * 4;
    int t = threadIdx.x;
    for (int idx = t; idx < 4 * DD; idx += 256)
        gs[idx >> 8][idx & 255] = g[(size_t)b0 * DD + idx];
    __syncthreads();

    float a1[4] = {0.f, 0.f, 0.f, 0.f}, a2[4] = {0.f, 0.f, 0.f, 0.f};
    for (int k = 0; k < DD; k += 2) {
        float w1a = Wr1[k * DD + t], w1b = Wr1[(k + 1) * DD + t];
        float w2a = Ws1[k * DD + t], w2b = Ws1[(k + 1) * DD + t];
#pragma unroll
        for (int gg = 0; gg < 4; ++gg) {
            float2 gv = *(const float2*)&gs[gg][k];
            a1[gg] = fmaf(gv.x, w1a, a1[gg]);
            a1[gg] = fmaf(gv.y, w1b, a1[gg]);
            a2[gg] = fmaf(gv.x, w2a, a2[gg]);
            a2[gg] = fmaf(gv.y, w2b, a2[gg]);
        }
    }
#pragma unroll
    for (int gg = 0; gg < 4; ++gg) {
        t1s[gg][t] = fmaxf(a1[gg] + br1[t], 0.f);
        gtop[gg][t] = a2[gg] + bs1[t];
    }
    __syncthreads();

    if (t < 4 * CC) {
        int gg = t / CC, c = t - gg * CC;
        float acc = br2[c];
        for (int d = 0; d < DD; ++d) acc = fmaf(t1s[gg][d], Wr2[d * CC + c], acc);
        logits[gg][c] = acc;
    }
    __syncthreads();
    if (t < 4 * CC) {
        int gg = t / CC, c = t - gg * CC;
        float m = -1e30f;
        for (int cc = 0; cc < CC; ++cc) m = fmaxf(m, logits[gg][cc]);
        float s = 0.f;
        for (int cc = 0; cc < CC; ++cc) s += __expf(logits[gg][cc] - m);
        probs[gg][c] = __expf(logits[gg][c] - m) / s;
    }
    __syncthreads();

    float wd = Ws2[t];
    float sacc[4];
#pragma unroll
    for (int gg = 0; gg < 4; ++gg) {
        float gt = gtop[gg][t];
        float acc = 0.f;
#pragma unroll
        for (int c = 0; c < CC; ++c)
            acc = fmaf(probs[gg][c], fmaxf(gt + EB[c * DD + t], 0.f), acc);
        sacc[gg] = acc * wd;
    }
#pragma unroll
    for (int gg = 0; gg < 4; ++gg) {
        float v = sacc[gg];
#pragma unroll
        for (int off = 32; off > 0; off >>= 1) v += __shfl_down(v, off, 64);
        if ((t & 63) == 0) red[t >> 6][gg] = v;
    }
    __syncthreads();
    if (t < 4)
        out[b0 + t] = red[0][t] + red[1][t] + red[2][t] + red[3][t] + bs2[0];
}

extern "C" void kernel_launch(void* const* d_in, const int* in_sizes, int n_in,
                              void* d_out, int out_size, void* d_ws, size_t ws_size,
                              hipStream_t stream)
{
    const float* x     = (const float*)d_in[0];
    const float* Win   = (const float*)d_in[3];
    const float* bin   = (const float*)d_in[4];
    const float* Wl    = (const float*)d_in[5];
    const float* Wr    = (const float*)d_in[6];
    const float* att   = (const float*)d_in[7];
    const float* Wr1   = (const float*)d_in[8];
    const float* br1   = (const float*)d_in[9];
    const float* Wr2   = (const float*)d_in[10];
    const float* br2   = (const float*)d_in[11];
    const float* Erecv = (const float*)d_in[12];
    const float* Ws1   = (const float*)d_in[13];
    const float* bs1   = (const float*)d_in[14];
    const float* Ws2   = (const float*)d_in[15];
    const float* bs2   = (const float*)d_in[16];
    float* out = (float*)d_out;

    short* Ah = (short*)d_ws;                       // [512][12288]
    short* Al = Ah + (size_t)NPAIR * APAIR;
    short* Bh = Al + (size_t)NPAIR * APAIR;         // [3][32][4096]
    short* Bl = Bh + (size_t)3 * 131072;
    float* g  = (float*)(Bl + (size_t)3 * 131072);  // [B][DD]
    float* EB = g + (size_t)BBATCH * DD;            // [CC][DD]

    k_prep_w<<<dim3(96), dim3(256), 0, stream>>>(Wl, Wr, Bh, Bl);
    k_in_proj<<<dim3(BBATCH), dim3(256), 0, stream>>>(x, Win, bin, Ah, Al);

    for (int l = 0; l < 3; ++l) {
        k_layer<<<dim3(NPAIR), dim3(512), 0, stream>>>(Ah, Al,
            Bh + (size_t)l * 131072, Bl + (size_t)l * 131072,
            att + (size_t)l * DD, (l == 2) ? g : nullptr);
    }

    k_eb<<<dim3(CC), dim3(256), 0, stream>>>(Erecv, Ws1, EB);
    k_head<<<dim3(256), dim3(256), 0, stream>>>(g, Wr1, br1, Wr2, br2,
                                                Ws1, bs1, Ws2, bs2, EB, out);
}